// Round 7
// baseline (286.358 us; speedup 1.0000x reference)
//
#include <hip/hip_runtime.h>
#include <hip/hip_bf16.h>
#include <math.h>

// ---------------------------------------------------------------------------
// GAT x2 + folded (v-proj -> out-proj -> fc) + log_softmax
//   CSR build: bucket-binning (128-node buckets), esrc uint16.
//   gemm1: MFMA bf16 16x16x32, 64x64 tile.
//   gat_agg64_g2: fused single-pass softmax-aggregate with phase-A/B weight
//     precompute (1 exp per edge-head, distributed via bpermute) + fused
//     gemm2 (h2 = elu(agg)+b1 @ W2) + al2s/al2d. hout1 never materialized.
//   gat_agg32_fin: same phase-A/B + fused final (M matvec + log_softmax).
// ---------------------------------------------------------------------------

#define BSHIFT 7
#define BMASK  ((1 << BSHIFT) - 1)
#define MAXNB  512
#define TILE   8192
#define XST    136

typedef __attribute__((ext_vector_type(8))) short short8;
typedef __attribute__((ext_vector_type(4))) float floatx4;

__device__ __forceinline__ unsigned short f2bf(float f) {
    union { float f; unsigned int u; } v; v.f = f;
    unsigned int u = v.u;
    return (unsigned short)((u + 0x7FFFu + ((u >> 16) & 1u)) >> 16);  // RNE
}
__device__ __forceinline__ float bfl2f(unsigned int p) {
    return __uint_as_float(p << 16);
}
__device__ __forceinline__ float bfh2f(unsigned int p) {
    return __uint_as_float(p & 0xFFFF0000u);
}
__device__ __forceinline__ float lrelu(float e) { return fmaxf(e, 0.2f * e); }

// ---------------- CSR build (bucket binning) ----------------
__global__ __launch_bounds__(256) void bin_count_kernel(
    const int* __restrict__ ei, int E, int Et, int NB,
    int* __restrict__ bcount) {
    __shared__ int h[MAXNB];
    for (int i = threadIdx.x; i < NB; i += 256) h[i] = 0;
    __syncthreads();
    int tile0 = blockIdx.x * TILE;
    int jend = tile0 + TILE; if (jend > Et) jend = Et;
    for (int j = tile0 + threadIdx.x; j < jend; j += 256) {
        int d = (j < E) ? ei[E + j] : (j - E);
        atomicAdd(&h[d >> BSHIFT], 1);
    }
    __syncthreads();
    for (int i = threadIdx.x; i < NB; i += 256)
        if (h[i]) atomicAdd(&bcount[i], h[i]);
}

__global__ __launch_bounds__(512) void bucket_scan_kernel(
    const int* __restrict__ bcount, int* __restrict__ bbase,
    int* __restrict__ gcur, int NB) {
    __shared__ int s[512];
    int t = threadIdx.x;
    int v = (t < NB) ? bcount[t] : 0;
    s[t] = v;
    __syncthreads();
    for (int off = 1; off < 512; off <<= 1) {
        int u = (t >= off) ? s[t - off] : 0;
        __syncthreads();
        s[t] += u;
        __syncthreads();
    }
    if (t < NB) { int b = s[t] - v; bbase[t] = b; gcur[t] = b; }
}

__global__ __launch_bounds__(256) void bin_scatter_kernel(
    const int* __restrict__ ei, int E, int Et, int NB,
    int* __restrict__ gcur, unsigned int* __restrict__ rec) {
    __shared__ int h[MAXNB];
    __shared__ int cur[MAXNB];
    for (int i = threadIdx.x; i < NB; i += 256) h[i] = 0;
    __syncthreads();
    int tile0 = blockIdx.x * TILE;
    int jend = tile0 + TILE; if (jend > Et) jend = Et;
    for (int j = tile0 + threadIdx.x; j < jend; j += 256) {
        int d = (j < E) ? ei[E + j] : (j - E);
        atomicAdd(&h[d >> BSHIFT], 1);
    }
    __syncthreads();
    for (int i = threadIdx.x; i < NB; i += 256)
        cur[i] = atomicAdd(&gcur[i], h[i]);
    __syncthreads();
    for (int j = tile0 + threadIdx.x; j < jend; j += 256) {
        int srcv, d;
        if (j < E) { srcv = ei[j]; d = ei[E + j]; } else { srcv = j - E; d = j - E; }
        int b = d >> BSHIFT;
        int pos = atomicAdd(&cur[b], 1);
        rec[pos] = (unsigned)srcv | ((unsigned)(d & BMASK) << 16);
    }
}

__global__ __launch_bounds__(256) void csr_finalize_kernel(
    const unsigned int* __restrict__ rec, const int* __restrict__ bcount,
    const int* __restrict__ bbase, int* __restrict__ rowp,
    unsigned short* __restrict__ esrc, int N, int Et) {
    __shared__ int h[128];
    __shared__ int nb[128];
    __shared__ int cur[128];
    int b = blockIdx.x, t = threadIdx.x;
    int base = bbase[b], cnt = bcount[b];
    if (t < 128) h[t] = 0;
    __syncthreads();
    for (int i = t; i < cnt; i += 256)
        atomicAdd(&h[(rec[base + i] >> 16) & 127], 1);
    __syncthreads();
    if (t == 0) {
        int run = base;
        for (int i = 0; i < 128; ++i) { nb[i] = run; run += h[i]; }
    }
    __syncthreads();
    if (t < 128) cur[t] = nb[t];
    int n0 = b << BSHIFT;
    if (t < 128 && n0 + t < N) rowp[n0 + t] = nb[t];
    if (b == 0 && t == 0) rowp[N] = Et;
    __syncthreads();
    for (int i = t; i < cnt; i += 256) {
        unsigned r = rec[base + i];
        int pos = atomicAdd(&cur[(r >> 16) & 127], 1);
        esrc[pos] = (unsigned short)(r & 0xFFFFu);
    }
}

// ---------------- gemm1 via MFMA ----------------
__global__ __launch_bounds__(256) void gemm1_mfma_kernel(
    const float* __restrict__ x, const float* __restrict__ W,
    const float* __restrict__ a_src, const float* __restrict__ a_dst,
    __hip_bfloat16* __restrict__ h, float* __restrict__ als,
    float* __restrict__ ald, int N) {
    __shared__ __align__(16) unsigned short xs[64 * XST];
    __shared__ __align__(16) unsigned short wt[64 * XST];
    int t = threadIdx.x;
    int nb = blockIdx.x * 64;
#pragma unroll
    for (int r = 0; r < 8; ++r) {
        int p = t + 256 * r;
        int row = p >> 5;
        int c4  = p & 31;
        int n = nb + row;
        float4 v = (n < N) ? ((const float4*)x)[(size_t)n * 32 + c4]
                           : make_float4(0.f, 0.f, 0.f, 0.f);
        unsigned short* dst = &xs[row * XST + c4 * 4];
        dst[0] = f2bf(v.x); dst[1] = f2bf(v.y);
        dst[2] = f2bf(v.z); dst[3] = f2bf(v.w);
    }
    {
        int n = t & 63, kg = t >> 6;
#pragma unroll
        for (int c = 0; c < 4; ++c) {
            int k0 = kg * 32 + c * 8;
            unsigned short* dst = &wt[n * XST + k0];
#pragma unroll
            for (int j = 0; j < 8; ++j)
                dst[j] = f2bf(W[(k0 + j) * 64 + n]);
        }
    }
    __syncthreads();
    int wave = t >> 6, lane = t & 63;
    int m16 = lane & 15, quad = lane >> 4;
    floatx4 acc[4];
#pragma unroll
    for (int i = 0; i < 4; ++i) acc[i] = (floatx4){0.f, 0.f, 0.f, 0.f};
#pragma unroll
    for (int k = 0; k < 4; ++k) {
        int koff = k * 32 + quad * 8;
        short8 afrag = *(const short8*)&xs[(wave * 16 + m16) * XST + koff];
#pragma unroll
        for (int nt = 0; nt < 4; ++nt) {
            short8 bfrag = *(const short8*)&wt[(nt * 16 + m16) * XST + koff];
            acc[nt] = __builtin_amdgcn_mfma_f32_16x16x32_bf16(afrag, bfrag, acc[nt], 0, 0, 0);
        }
    }
    __syncthreads();
    float* hs = (float*)xs;                // [64][65]
#pragma unroll
    for (int nt = 0; nt < 4; ++nt)
#pragma unroll
        for (int r = 0; r < 4; ++r)
            hs[(wave * 16 + quad * 4 + r) * 65 + nt * 16 + m16] = acc[nt][r];
    __syncthreads();
    float asv = a_src[lane], adv = a_dst[lane];
    for (int itn = 0; itn < 16; ++itn) {
        int nl = wave * 16 + itn;
        int n = nb + nl;
        if (n >= N) break;
        float v = hs[nl * 65 + lane];
        h[(size_t)n * 64 + lane] = __float2bfloat16(v);
        float ps = v * asv, pd = v * adv;
        ps += __shfl_xor(ps, 1); ps += __shfl_xor(ps, 2); ps += __shfl_xor(ps, 4);
        pd += __shfl_xor(pd, 1); pd += __shfl_xor(pd, 2); pd += __shfl_xor(pd, 4);
        if ((lane & 7) == 0) {
            als[n * 8 + (lane >> 3)] = ps;
            ald[n * 8 + (lane >> 3)] = pd;
        }
    }
}

// ---------------- agg layer 1 + fused gemm2 ----------------
// One wave per node. Phase A (per 8-edge chunk): lane = e*8+h computes the
// (edge,head) weight ONCE; denominator accumulated there. Phase B: weights &
// src distributed via bpermute; 2 edges/iter, lane covers ch 2l,2l+1.
// Epilogue: o = elu(agg/d + b1); fused h2 = o @ W2 (split-k over halves);
// writes h2(bf16), al2s, al2d.
__global__ __launch_bounds__(256) void gat_agg64_g2_kernel(
    const int* __restrict__ rowp, const unsigned short* __restrict__ esrc,
    const __hip_bfloat16* __restrict__ feat, const float* __restrict__ als,
    const float* __restrict__ ald_arr, const float* __restrict__ bias,
    const float* __restrict__ W2, const float* __restrict__ a2s,
    const float* __restrict__ a2d,
    __hip_bfloat16* __restrict__ h2out, float* __restrict__ als2,
    float* __restrict__ ald2, int N) {
    __shared__ float W2s[64 * 32];
    int t = threadIdx.x;
    for (int i = t; i < 2048; i += 256) W2s[i] = W2[i];
    __syncthreads();
    const int lane = t & 63;
    const int half = lane >> 5;
    const int l = lane & 31;
    const int hd = l >> 2;               // head of channels 2l,2l+1 (C=8)
    const int hA = lane & 7;             // phase-A head
    const int eA = lane >> 3;            // phase-A edge slot (0..7)
    int n = blockIdx.x * 4 + (t >> 6);
    if (n >= N) return;
    float aldA = ald_arr[n * 8 + hA];
    float a2sv = a2s[l], a2dv = a2d[l];
    int beg = rowp[n];
    int cnt = rowp[n + 1] - beg;
    float p0 = 0.f, p1 = 0.f, dsum = 0.f;
    const unsigned int* fp = (const unsigned int*)feat;
    for (int c = 0; c < cnt; c += 8) {
        int rem = cnt - c;               // >0
        int ec = (eA < rem) ? eA : rem - 1;
        int sA = esrc[beg + c + ec];
        float ev = als[sA * 8 + hA] + aldA;
        float w = (eA < rem) ? __expf(lrelu(ev)) : 0.f;
        dsum += w;
#pragma unroll
        for (int ep = 0; ep < 4; ++ep) {
            int srcl = (2 * ep + half) * 8;
            int s = __shfl(sA, srcl);            // clamped-valid
            float wv = __shfl(w, srcl + hd);     // 0 for phantom edges
            unsigned g = fp[s * 32 + l];
            p0 += wv * bfl2f(g);
            p1 += wv * bfh2f(g);
        }
    }
    dsum += __shfl_xor(dsum, 8);
    dsum += __shfl_xor(dsum, 16);
    dsum += __shfl_xor(dsum, 32);        // per-head totals, head = lane&7
    float dv = __shfl(dsum, hd);         // lane hd holds head hd
    p0 += __shfl_xor(p0, 32);
    p1 += __shfl_xor(p1, 32);
    float inv = 1.f / (dv + 1e-16f);
    float2 bv = ((const float2*)bias)[l];
    float o0 = p0 * inv + bv.x;
    float o1 = p1 * inv + bv.y;
    o0 = (o0 > 0.f) ? o0 : (__expf(o0) - 1.f);
    o1 = (o1 > 0.f) ? o1 : (__expf(o1) - 1.f);
    // fused gemm2: h2[l] = sum_k o[k]*W2[k][l], split-k over wave halves
    float acc = 0.f;
#pragma unroll
    for (int kk = 0; kk < 32; ++kk) {
        int k = half * 32 + kk;
        float ov = __shfl((kk & 1) ? o1 : o0, half * 16 + (kk >> 1));
        acc += ov * W2s[k * 32 + l];
    }
    acc += __shfl_xor(acc, 32);
    // attention logits for layer 2 (l = hd2*4 + c, C=4)
    float ps = acc * a2sv, pd = acc * a2dv;
    ps += __shfl_xor(ps, 1); ps += __shfl_xor(ps, 2);
    pd += __shfl_xor(pd, 1); pd += __shfl_xor(pd, 2);
    if (half == 0) {
        h2out[(size_t)n * 32 + l] = __float2bfloat16(acc);
        if ((l & 3) == 0) {
            als2[n * 8 + (l >> 2)] = ps;
            ald2[n * 8 + (l >> 2)] = pd;
        }
    }
}

// ---------------- agg layer 2 + fused final ----------------
// 2 nodes/wave (half-wave each). Phase A: chunk of 4 edges (lane-in-half =
// e*8+h). Phase B: 2 edges/iter, 16 lanes x 2 channels. Epilogue: o = elu(.),
// fused logits = M @ o + bf (split-k over subs), log_softmax, write out.
__global__ __launch_bounds__(256) void gat_agg32_fin_kernel(
    const int* __restrict__ rowp, const unsigned short* __restrict__ esrc,
    const __hip_bfloat16* __restrict__ feat, const float* __restrict__ als,
    const float* __restrict__ ald_arr, const float* __restrict__ bias,
    const float* __restrict__ M, const float* __restrict__ bf,
    float* __restrict__ out, int N) {
    __shared__ float Ms[16 * 33];
    __shared__ float bfs[16];
    int t = threadIdx.x;
    for (int i = t; i < 512; i += 256) Ms[(i >> 5) * 33 + (i & 31)] = M[i];
    if (t < 16) bfs[t] = bf[t];
    __syncthreads();
    const int lane = t & 63;
    const int nh = lane >> 5;            // node within wave
    const int l = lane & 31;
    const int sub = l >> 4;              // edge slot / k-half
    const int j = l & 15;                // channel pair -> ch 2j,2j+1
    const int hd2 = j >> 1;              // head (C=4)
    const int hA = l & 7;
    const int eA = l >> 3;               // 0..3
    const int nbase = nh * 32;
    int n = (blockIdx.x * 4 + (t >> 6)) * 2 + nh;
    bool valid = (n < N);
    int nn = valid ? n : 0;
    float aldA = ald_arr[nn * 8 + hA];
    int beg = rowp[nn];
    int cnt = valid ? (rowp[nn + 1] - beg) : 0;
    float p0 = 0.f, p1 = 0.f, dsum = 0.f;
    const unsigned int* fp = (const unsigned int*)feat;
    for (int c = 0; c < cnt; c += 4) {
        int rem = cnt - c;
        int ec = (eA < rem) ? eA : rem - 1;
        int sA = esrc[beg + c + ec];
        float ev = als[sA * 8 + hA] + aldA;
        float w = (eA < rem) ? __expf(lrelu(ev)) : 0.f;
        dsum += w;
#pragma unroll
        for (int ep = 0; ep < 2; ++ep) {
            int srcl = nbase + (2 * ep + sub) * 8;
            int s = __shfl(sA, srcl);
            float wv = __shfl(w, srcl + hd2);
            unsigned g = fp[s * 16 + j];
            p0 += wv * bfl2f(g);
            p1 += wv * bfh2f(g);
        }
    }
    dsum += __shfl_xor(dsum, 8);
    dsum += __shfl_xor(dsum, 16);        // per-head totals within node group
    float dv = __shfl(dsum, nbase + hd2);
    p0 += __shfl_xor(p0, 16);
    p1 += __shfl_xor(p1, 16);
    float inv = 1.f / (dv + 1e-16f);
    float2 bv = ((const float2*)bias)[j];
    float o0 = p0 * inv + bv.x;
    float o1 = p1 * inv + bv.y;
    o0 = (o0 > 0.f) ? o0 : (__expf(o0) - 1.f);
    o1 = (o1 > 0.f) ? o1 : (__expf(o1) - 1.f);
    // fused final: logits[c] = sum_k M[c][k]*o[k] + bf[c]; c = j, split-k on sub
    const int cc = j;
    float part = 0.f;
#pragma unroll
    for (int kk = 0; kk < 16; ++kk) {
        int k = sub * 16 + kk;
        float ov = __shfl((k & 1) ? o1 : o0, nbase + (k >> 1));
        part += ov * Ms[cc * 33 + k];
    }
    part += __shfl_xor(part, 16);
    float logit = part + bfs[cc];
    float mx = logit;
    mx = fmaxf(mx, __shfl_xor(mx, 1));
    mx = fmaxf(mx, __shfl_xor(mx, 2));
    mx = fmaxf(mx, __shfl_xor(mx, 4));
    mx = fmaxf(mx, __shfl_xor(mx, 8));
    float ex = __expf(logit - mx);
    float se = ex;
    se += __shfl_xor(se, 1);
    se += __shfl_xor(se, 2);
    se += __shfl_xor(se, 4);
    se += __shfl_xor(se, 8);
    float res = logit - (mx + __logf(se));
    if (valid && sub == 0) out[(size_t)n * 16 + cc] = res;
}

// ---------------- fold ----------------
__global__ __launch_bounds__(256) void fold_kernel(
    const float* __restrict__ in_proj_w, const float* __restrict__ in_proj_b,
    const float* __restrict__ out_proj_w, const float* __restrict__ out_proj_b,
    const float* __restrict__ fc_w, const float* __restrict__ fc_b,
    float* __restrict__ M, float* __restrict__ bf) {
    __shared__ float Wvo[32 * 32];
    __shared__ float bvo[32];
    const float* Wv = in_proj_w + 64 * 32;
    const float* bv = in_proj_b + 64;
    int t = threadIdx.x;
    for (int idx = t; idx < 1024; idx += 256) {
        int i = idx >> 5, j = idx & 31;
        float s = 0.f;
        for (int k = 0; k < 32; ++k) s += out_proj_w[i * 32 + k] * Wv[k * 32 + j];
        Wvo[idx] = s;
    }
    if (t < 32) {
        float s = 0.f;
        for (int k = 0; k < 32; ++k) s += out_proj_w[t * 32 + k] * bv[k];
        bvo[t] = s + out_proj_b[t];
    }
    __syncthreads();
    for (int idx = t; idx < 16 * 32; idx += 256) {
        int c = idx >> 5, j = idx & 31;
        float s = 0.f;
        for (int i = 0; i < 32; ++i) s += fc_w[c * 32 + i] * Wvo[i * 32 + j];
        M[idx] = s;
    }
    if (t < 16) {
        float s = 0.f;
        for (int i = 0; i < 32; ++i) s += fc_w[t * 32 + i] * bvo[i];
        bf[t] = s + fc_b[t];
    }
}

extern "C" void kernel_launch(void* const* d_in, const int* in_sizes, int n_in,
                              void* d_out, int out_size, void* d_ws, size_t ws_size,
                              hipStream_t stream) {
    const float* x   = (const float*)d_in[0];
    const int*   ei  = (const int*)d_in[1];
    const float* W1  = (const float*)d_in[2];
    const float* a1s = (const float*)d_in[3];
    const float* a1d = (const float*)d_in[4];
    const float* b1  = (const float*)d_in[5];
    const float* W2  = (const float*)d_in[6];
    const float* a2s = (const float*)d_in[7];
    const float* a2d = (const float*)d_in[8];
    const float* b2  = (const float*)d_in[9];
    const float* ipw = (const float*)d_in[10];
    const float* ipb = (const float*)d_in[11];
    const float* opw = (const float*)d_in[12];
    const float* opb = (const float*)d_in[13];
    const float* fcw = (const float*)d_in[14];
    const float* fcb = (const float*)d_in[15];
    float* out = (float*)d_out;

    int N = in_sizes[0] / 128;
    int E = in_sizes[1] / 2;
    int Et = E + N;
    int NB = (N + BMASK) >> BSHIFT;
    int NTILES = (Et + TILE - 1) / TILE;

    char* ws = (char*)d_ws;
    size_t off = 0;
    auto alloc = [&](size_t bytes) -> void* {
        void* p = ws + off;
        off += bytes;
        off = (off + 255) & ~(size_t)255;
        return p;
    };
    int*   bcount = (int*)alloc(MAXNB * 4);
    int*   bbase  = (int*)alloc(MAXNB * 4);
    int*   gcur   = (int*)alloc(MAXNB * 4);
    unsigned int*   rec  = (unsigned int*)alloc((size_t)Et * 4);
    int*   rowp   = (int*)alloc((size_t)(N + 1) * 4);
    unsigned short* esrc = (unsigned short*)alloc((size_t)Et * 2);
    __hip_bfloat16* h1 = (__hip_bfloat16*)alloc((size_t)N * 64 * 2);
    float* al1s  = (float*)alloc((size_t)N * 8 * 4);
    float* al1d  = (float*)alloc((size_t)N * 8 * 4);
    __hip_bfloat16* h2 = (__hip_bfloat16*)alloc((size_t)N * 32 * 2);
    float* al2s  = (float*)alloc((size_t)N * 8 * 4);
    float* al2d  = (float*)alloc((size_t)N * 8 * 4);
    float* Mf    = (float*)alloc(512 * 4);
    float* bff   = (float*)alloc(16 * 4);
    (void)ws_size; (void)n_in; (void)out_size;

    hipMemsetAsync(bcount, 0, MAXNB * 4, stream);
    bin_count_kernel<<<NTILES, 256, 0, stream>>>(ei, E, Et, NB, bcount);
    bucket_scan_kernel<<<1, 512, 0, stream>>>(bcount, bbase, gcur, NB);
    bin_scatter_kernel<<<NTILES, 256, 0, stream>>>(ei, E, Et, NB, gcur, rec);
    csr_finalize_kernel<<<NB, 256, 0, stream>>>(rec, bcount, bbase, rowp, esrc, N, Et);

    gemm1_mfma_kernel<<<(N + 63) / 64, 256, 0, stream>>>(x, W1, a1s, a1d, h1, al1s, al1d, N);
    fold_kernel<<<1, 256, 0, stream>>>(ipw, ipb, opw, opb, fcw, fcb, Mf, bff);
    gat_agg64_g2_kernel<<<(N + 3) / 4, 256, 0, stream>>>(
        rowp, esrc, h1, al1s, al1d, b1, W2, a2s, a2d, h2, al2s, al2d, N);
    gat_agg32_fin_kernel<<<(N + 7) / 8, 256, 0, stream>>>(
        rowp, esrc, h2, al2s, al2d, b2, Mf, bff, out, N);
}

// Round 8
// 266.336 us; speedup vs baseline: 1.0752x; 1.0752x over previous
//
#include <hip/hip_runtime.h>
#include <hip/hip_bf16.h>
#include <math.h>

// ---------------------------------------------------------------------------
// GAT x2 + folded (v-proj -> out-proj -> fc) + log_softmax
//   CSR build: bucket-binning (128-node buckets), esrc uint16.
//   gemm1: MFMA bf16 16x16x32, 64x64 tile.
//   gat_agg64_g2: R5-style fused single-pass softmax-aggregate (independent
//     gather streams, redundant exp -- faster than phase-A/B shuffle chain,
//     see R6 post-mortem) + fused gemm2 epilogue (h2 = elu(agg)+b1 @ W2).
//   gat_agg32_fin: same + fused final (M matvec + log_softmax).
// ---------------------------------------------------------------------------

#define BSHIFT 7
#define BMASK  ((1 << BSHIFT) - 1)
#define MAXNB  512
#define TILE   8192
#define XST    136

typedef __attribute__((ext_vector_type(8))) short short8;
typedef __attribute__((ext_vector_type(4))) float floatx4;

__device__ __forceinline__ unsigned short f2bf(float f) {
    union { float f; unsigned int u; } v; v.f = f;
    unsigned int u = v.u;
    return (unsigned short)((u + 0x7FFFu + ((u >> 16) & 1u)) >> 16);  // RNE
}
__device__ __forceinline__ float bfl2f(unsigned int p) {
    return __uint_as_float(p << 16);
}
__device__ __forceinline__ float bfh2f(unsigned int p) {
    return __uint_as_float(p & 0xFFFF0000u);
}
__device__ __forceinline__ float lrelu(float e) { return fmaxf(e, 0.2f * e); }

// ---------------- CSR build (bucket binning) ----------------
__global__ __launch_bounds__(256) void bin_count_kernel(
    const int* __restrict__ ei, int E, int Et, int NB,
    int* __restrict__ bcount) {
    __shared__ int h[MAXNB];
    for (int i = threadIdx.x; i < NB; i += 256) h[i] = 0;
    __syncthreads();
    int tile0 = blockIdx.x * TILE;
    int jend = tile0 + TILE; if (jend > Et) jend = Et;
    for (int j = tile0 + threadIdx.x; j < jend; j += 256) {
        int d = (j < E) ? ei[E + j] : (j - E);
        atomicAdd(&h[d >> BSHIFT], 1);
    }
    __syncthreads();
    for (int i = threadIdx.x; i < NB; i += 256)
        if (h[i]) atomicAdd(&bcount[i], h[i]);
}

__global__ __launch_bounds__(512) void bucket_scan_kernel(
    const int* __restrict__ bcount, int* __restrict__ bbase,
    int* __restrict__ gcur, int NB) {
    __shared__ int s[512];
    int t = threadIdx.x;
    int v = (t < NB) ? bcount[t] : 0;
    s[t] = v;
    __syncthreads();
    for (int off = 1; off < 512; off <<= 1) {
        int u = (t >= off) ? s[t - off] : 0;
        __syncthreads();
        s[t] += u;
        __syncthreads();
    }
    if (t < NB) { int b = s[t] - v; bbase[t] = b; gcur[t] = b; }
}

__global__ __launch_bounds__(256) void bin_scatter_kernel(
    const int* __restrict__ ei, int E, int Et, int NB,
    int* __restrict__ gcur, unsigned int* __restrict__ rec) {
    __shared__ int h[MAXNB];
    __shared__ int cur[MAXNB];
    for (int i = threadIdx.x; i < NB; i += 256) h[i] = 0;
    __syncthreads();
    int tile0 = blockIdx.x * TILE;
    int jend = tile0 + TILE; if (jend > Et) jend = Et;
    for (int j = tile0 + threadIdx.x; j < jend; j += 256) {
        int d = (j < E) ? ei[E + j] : (j - E);
        atomicAdd(&h[d >> BSHIFT], 1);
    }
    __syncthreads();
    for (int i = threadIdx.x; i < NB; i += 256)
        cur[i] = atomicAdd(&gcur[i], h[i]);
    __syncthreads();
    for (int j = tile0 + threadIdx.x; j < jend; j += 256) {
        int srcv, d;
        if (j < E) { srcv = ei[j]; d = ei[E + j]; } else { srcv = j - E; d = j - E; }
        int b = d >> BSHIFT;
        int pos = atomicAdd(&cur[b], 1);
        rec[pos] = (unsigned)srcv | ((unsigned)(d & BMASK) << 16);
    }
}

__global__ __launch_bounds__(256) void csr_finalize_kernel(
    const unsigned int* __restrict__ rec, const int* __restrict__ bcount,
    const int* __restrict__ bbase, int* __restrict__ rowp,
    unsigned short* __restrict__ esrc, int N, int Et) {
    __shared__ int h[128];
    __shared__ int nb[128];
    __shared__ int cur[128];
    int b = blockIdx.x, t = threadIdx.x;
    int base = bbase[b], cnt = bcount[b];
    if (t < 128) h[t] = 0;
    __syncthreads();
    for (int i = t; i < cnt; i += 256)
        atomicAdd(&h[(rec[base + i] >> 16) & 127], 1);
    __syncthreads();
    if (t == 0) {
        int run = base;
        for (int i = 0; i < 128; ++i) { nb[i] = run; run += h[i]; }
    }
    __syncthreads();
    if (t < 128) cur[t] = nb[t];
    int n0 = b << BSHIFT;
    if (t < 128 && n0 + t < N) rowp[n0 + t] = nb[t];
    if (b == 0 && t == 0) rowp[N] = Et;
    __syncthreads();
    for (int i = t; i < cnt; i += 256) {
        unsigned r = rec[base + i];
        int pos = atomicAdd(&cur[(r >> 16) & 127], 1);
        esrc[pos] = (unsigned short)(r & 0xFFFFu);
    }
}

// ---------------- gemm1 via MFMA ----------------
__global__ __launch_bounds__(256) void gemm1_mfma_kernel(
    const float* __restrict__ x, const float* __restrict__ W,
    const float* __restrict__ a_src, const float* __restrict__ a_dst,
    __hip_bfloat16* __restrict__ h, float* __restrict__ als,
    float* __restrict__ ald, int N) {
    __shared__ __align__(16) unsigned short xs[64 * XST];
    __shared__ __align__(16) unsigned short wt[64 * XST];
    int t = threadIdx.x;
    int nb = blockIdx.x * 64;
#pragma unroll
    for (int r = 0; r < 8; ++r) {
        int p = t + 256 * r;
        int row = p >> 5;
        int c4  = p & 31;
        int n = nb + row;
        float4 v = (n < N) ? ((const float4*)x)[(size_t)n * 32 + c4]
                           : make_float4(0.f, 0.f, 0.f, 0.f);
        unsigned short* dst = &xs[row * XST + c4 * 4];
        dst[0] = f2bf(v.x); dst[1] = f2bf(v.y);
        dst[2] = f2bf(v.z); dst[3] = f2bf(v.w);
    }
    {
        int n = t & 63, kg = t >> 6;
#pragma unroll
        for (int c = 0; c < 4; ++c) {
            int k0 = kg * 32 + c * 8;
            unsigned short* dst = &wt[n * XST + k0];
#pragma unroll
            for (int j = 0; j < 8; ++j)
                dst[j] = f2bf(W[(k0 + j) * 64 + n]);
        }
    }
    __syncthreads();
    int wave = t >> 6, lane = t & 63;
    int m16 = lane & 15, quad = lane >> 4;
    floatx4 acc[4];
#pragma unroll
    for (int i = 0; i < 4; ++i) acc[i] = (floatx4){0.f, 0.f, 0.f, 0.f};
#pragma unroll
    for (int k = 0; k < 4; ++k) {
        int koff = k * 32 + quad * 8;
        short8 afrag = *(const short8*)&xs[(wave * 16 + m16) * XST + koff];
#pragma unroll
        for (int nt = 0; nt < 4; ++nt) {
            short8 bfrag = *(const short8*)&wt[(nt * 16 + m16) * XST + koff];
            acc[nt] = __builtin_amdgcn_mfma_f32_16x16x32_bf16(afrag, bfrag, acc[nt], 0, 0, 0);
        }
    }
    __syncthreads();
    float* hs = (float*)xs;                // [64][65]
#pragma unroll
    for (int nt = 0; nt < 4; ++nt)
#pragma unroll
        for (int r = 0; r < 4; ++r)
            hs[(wave * 16 + quad * 4 + r) * 65 + nt * 16 + m16] = acc[nt][r];
    __syncthreads();
    float asv = a_src[lane], adv = a_dst[lane];
    for (int itn = 0; itn < 16; ++itn) {
        int nl = wave * 16 + itn;
        int n = nb + nl;
        if (n >= N) break;
        float v = hs[nl * 65 + lane];
        h[(size_t)n * 64 + lane] = __float2bfloat16(v);
        float ps = v * asv, pd = v * adv;
        ps += __shfl_xor(ps, 1); ps += __shfl_xor(ps, 2); ps += __shfl_xor(ps, 4);
        pd += __shfl_xor(pd, 1); pd += __shfl_xor(pd, 2); pd += __shfl_xor(pd, 4);
        if ((lane & 7) == 0) {
            als[n * 8 + (lane >> 3)] = ps;
            ald[n * 8 + (lane >> 3)] = pd;
        }
    }
}

// ---------------- agg layer 1 (R5 inner loop) + fused gemm2 ----------------
// One wave per node; 2 edges/iter (lanes 0-31 edge a, 32-63 edge b), each
// lane covers channels 2l,2l+1 via one bf16x2 load; unroll x4 pairs for MLP.
// Epilogue: o = elu(agg/d + b1); h2 = o @ W2 split-k over halves; al2s/al2d.
__global__ __launch_bounds__(256) void gat_agg64_g2_kernel(
    const int* __restrict__ rowp, const unsigned short* __restrict__ esrc,
    const __hip_bfloat16* __restrict__ feat, const float* __restrict__ als,
    const float* __restrict__ ald_arr, const float* __restrict__ bias,
    const float* __restrict__ W2, const float* __restrict__ a2s,
    const float* __restrict__ a2d,
    __hip_bfloat16* __restrict__ h2out, float* __restrict__ als2,
    float* __restrict__ ald2, int N) {
    __shared__ float W2s[64 * 32];
    int t = threadIdx.x;
    for (int i = t; i < 2048; i += 256) W2s[i] = W2[i];
    __syncthreads();
    const int lane = t & 63;
    const int half = lane >> 5;          // edge slot within pair
    const int l = lane & 31;             // channel-pair index
    const int hd = l >> 2;               // head of channels 2l,2l+1 (C=8)
    int n = blockIdx.x * 4 + (t >> 6);
    if (n >= N) return;
    float aldv = ald_arr[n * 8 + hd];
    int beg = rowp[n], end = rowp[n + 1];
    float d0 = 0.f, d1 = 0.f, d2 = 0.f, d3 = 0.f;
    float p00 = 0.f, p01 = 0.f, p10 = 0.f, p11 = 0.f;
    float p20 = 0.f, p21 = 0.f, p30 = 0.f, p31 = 0.f;
    const unsigned int* fp = (const unsigned int*)feat;
    int i = beg;
    for (; i + 8 <= end; i += 8) {
        int s0 = esrc[i + half];
        int s1 = esrc[i + 2 + half];
        int s2 = esrc[i + 4 + half];
        int s3 = esrc[i + 6 + half];
        float e0 = als[s0 * 8 + hd] + aldv;
        float e1 = als[s1 * 8 + hd] + aldv;
        float e2 = als[s2 * 8 + hd] + aldv;
        float e3 = als[s3 * 8 + hd] + aldv;
        unsigned g0 = fp[s0 * 32 + l];
        unsigned g1 = fp[s1 * 32 + l];
        unsigned g2 = fp[s2 * 32 + l];
        unsigned g3 = fp[s3 * 32 + l];
        float w0 = __expf(lrelu(e0));
        float w1 = __expf(lrelu(e1));
        float w2 = __expf(lrelu(e2));
        float w3 = __expf(lrelu(e3));
        d0 += w0; p00 += w0 * bfl2f(g0); p01 += w0 * bfh2f(g0);
        d1 += w1; p10 += w1 * bfl2f(g1); p11 += w1 * bfh2f(g1);
        d2 += w2; p20 += w2 * bfl2f(g2); p21 += w2 * bfh2f(g2);
        d3 += w3; p30 += w3 * bfl2f(g3); p31 += w3 * bfh2f(g3);
    }
    for (; i + 2 <= end; i += 2) {
        int s = esrc[i + half];
        float e = als[s * 8 + hd] + aldv;
        unsigned g = fp[s * 32 + l];
        float w = __expf(lrelu(e));
        d0 += w; p00 += w * bfl2f(g); p01 += w * bfh2f(g);
    }
    if (i < end) {                        // odd final edge: slot 0 only
        int s = esrc[end - 1];
        float e = als[s * 8 + hd] + aldv;
        unsigned g = fp[s * 32 + l];
        float w = (half == 0) ? __expf(lrelu(e)) : 0.f;
        d0 += w; p00 += w * bfl2f(g); p01 += w * bfh2f(g);
    }
    float d = (d0 + d1) + (d2 + d3);
    float a0 = (p00 + p10) + (p20 + p30);
    float a1 = (p01 + p11) + (p21 + p31);
    d  += __shfl_xor(d, 32);
    a0 += __shfl_xor(a0, 32);
    a1 += __shfl_xor(a1, 32);
    float inv = 1.f / (d + 1e-16f);
    float2 bv = ((const float2*)bias)[l];
    float o0 = a0 * inv + bv.x;
    float o1 = a1 * inv + bv.y;
    o0 = (o0 > 0.f) ? o0 : (__expf(o0) - 1.f);
    o1 = (o1 > 0.f) ? o1 : (__expf(o1) - 1.f);
    // fused gemm2: h2[l] = sum_k o[k]*W2[k][l], split-k over wave halves
    float acc = 0.f;
#pragma unroll
    for (int kk = 0; kk < 32; ++kk) {
        int k = half * 32 + kk;
        float ov = __shfl((kk & 1) ? o1 : o0, half * 16 + (kk >> 1));
        acc += ov * W2s[k * 32 + l];
    }
    acc += __shfl_xor(acc, 32);
    float ps = acc * a2s[l], pd = acc * a2d[l];
    ps += __shfl_xor(ps, 1); ps += __shfl_xor(ps, 2);
    pd += __shfl_xor(pd, 1); pd += __shfl_xor(pd, 2);
    if (half == 0) {
        h2out[(size_t)n * 32 + l] = __float2bfloat16(acc);
        if ((l & 3) == 0) {
            als2[n * 8 + (l >> 2)] = ps;
            ald2[n * 8 + (l >> 2)] = pd;
        }
    }
}

// ---------------- agg layer 2 (R5 inner loop) + fused final ----------------
// 2 nodes/wave; within half: 2 edges x 16 lanes x 2 channels. Epilogue:
// o = elu(.), logits = M @ o + bf (split-k over subs), log_softmax, store.
__global__ __launch_bounds__(256) void gat_agg32_fin_kernel(
    const int* __restrict__ rowp, const unsigned short* __restrict__ esrc,
    const __hip_bfloat16* __restrict__ feat, const float* __restrict__ als,
    const float* __restrict__ ald_arr, const float* __restrict__ bias,
    const float* __restrict__ M, const float* __restrict__ bf,
    float* __restrict__ out, int N) {
    __shared__ float Ms[16 * 33];
    __shared__ float bfs[16];
    int t = threadIdx.x;
    for (int i = t; i < 512; i += 256) Ms[(i >> 5) * 33 + (i & 31)] = M[i];
    if (t < 16) bfs[t] = bf[t];
    __syncthreads();
    const int lane = t & 63;
    const int nh = lane >> 5;            // node within wave
    const int l = lane & 31;
    const int sub = l >> 4;              // edge slot / k-half
    const int j = l & 15;                // channel pair -> ch 2j,2j+1
    const int hd2 = j >> 1;              // head (C=4)
    const int nbase = nh * 32;
    int n = (blockIdx.x * 4 + (t >> 6)) * 2 + nh;
    bool valid = (n < N);
    int nn = valid ? n : 0;
    float aldv = ald_arr[nn * 8 + hd2];
    int beg = rowp[nn];
    int end = valid ? rowp[nn + 1] : beg;
    float d0 = 0.f, d1 = 0.f, d2 = 0.f, d3 = 0.f;
    float p00 = 0.f, p01 = 0.f, p10 = 0.f, p11 = 0.f;
    float p20 = 0.f, p21 = 0.f, p30 = 0.f, p31 = 0.f;
    const unsigned int* fp = (const unsigned int*)feat;
    int i = beg;
    for (; i + 8 <= end; i += 8) {
        int s0 = esrc[i + sub];
        int s1 = esrc[i + 2 + sub];
        int s2 = esrc[i + 4 + sub];
        int s3 = esrc[i + 6 + sub];
        float e0 = als[s0 * 8 + hd2] + aldv;
        float e1 = als[s1 * 8 + hd2] + aldv;
        float e2 = als[s2 * 8 + hd2] + aldv;
        float e3 = als[s3 * 8 + hd2] + aldv;
        unsigned g0 = fp[s0 * 16 + j];
        unsigned g1 = fp[s1 * 16 + j];
        unsigned g2 = fp[s2 * 16 + j];
        unsigned g3 = fp[s3 * 16 + j];
        float w0 = __expf(lrelu(e0));
        float w1 = __expf(lrelu(e1));
        float w2 = __expf(lrelu(e2));
        float w3 = __expf(lrelu(e3));
        d0 += w0; p00 += w0 * bfl2f(g0); p01 += w0 * bfh2f(g0);
        d1 += w1; p10 += w1 * bfl2f(g1); p11 += w1 * bfh2f(g1);
        d2 += w2; p20 += w2 * bfl2f(g2); p21 += w2 * bfh2f(g2);
        d3 += w3; p30 += w3 * bfl2f(g3); p31 += w3 * bfh2f(g3);
    }
    for (; i + 2 <= end; i += 2) {
        int s = esrc[i + sub];
        float e = als[s * 8 + hd2] + aldv;
        unsigned g = fp[s * 16 + j];
        float w = __expf(lrelu(e));
        d0 += w; p00 += w * bfl2f(g); p01 += w * bfh2f(g);
    }
    if (i < end) {
        int s = esrc[end - 1];
        float e = als[s * 8 + hd2] + aldv;
        unsigned g = fp[s * 16 + j];
        float w = (sub == 0) ? __expf(lrelu(e)) : 0.f;
        d0 += w; p00 += w * bfl2f(g); p01 += w * bfh2f(g);
    }
    float d = (d0 + d1) + (d2 + d3);
    float a0 = (p00 + p10) + (p20 + p30);
    float a1 = (p01 + p11) + (p21 + p31);
    d  += __shfl_xor(d, 16);
    a0 += __shfl_xor(a0, 16);
    a1 += __shfl_xor(a1, 16);
    float inv = 1.f / (d + 1e-16f);
    float2 bv = ((const float2*)bias)[j];
    float o0 = a0 * inv + bv.x;
    float o1 = a1 * inv + bv.y;
    o0 = (o0 > 0.f) ? o0 : (__expf(o0) - 1.f);
    o1 = (o1 > 0.f) ? o1 : (__expf(o1) - 1.f);
    // fused final: logits[c] = sum_k M[c][k]*o[k] + bf[c]; c = j, split-k on sub
    const int cc = j;
    float part = 0.f;
#pragma unroll
    for (int kk = 0; kk < 16; ++kk) {
        int k = sub * 16 + kk;
        float ov = __shfl((k & 1) ? o1 : o0, nbase + (k >> 1));
        part += ov * Ms[cc * 33 + k];
    }
    part += __shfl_xor(part, 16);
    float logit = part + bfs[cc];
    float mx = logit;
    mx = fmaxf(mx, __shfl_xor(mx, 1));
    mx = fmaxf(mx, __shfl_xor(mx, 2));
    mx = fmaxf(mx, __shfl_xor(mx, 4));
    mx = fmaxf(mx, __shfl_xor(mx, 8));
    float ex = __expf(logit - mx);
    float se = ex;
    se += __shfl_xor(se, 1);
    se += __shfl_xor(se, 2);
    se += __shfl_xor(se, 4);
    se += __shfl_xor(se, 8);
    float res = logit - (mx + __logf(se));
    if (valid && sub == 0) out[(size_t)n * 16 + cc] = res;
}

// ---------------- fold ----------------
__global__ __launch_bounds__(256) void fold_kernel(
    const float* __restrict__ in_proj_w, const float* __restrict__ in_proj_b,
    const float* __restrict__ out_proj_w, const float* __restrict__ out_proj_b,
    const float* __restrict__ fc_w, const float* __restrict__ fc_b,
    float* __restrict__ M, float* __restrict__ bf) {
    __shared__ float Wvo[32 * 32];
    __shared__ float bvo[32];
    const float* Wv = in_proj_w + 64 * 32;
    const float* bv = in_proj_b + 64;
    int t = threadIdx.x;
    for (int idx = t; idx < 1024; idx += 256) {
        int i = idx >> 5, j = idx & 31;
        float s = 0.f;
        for (int k = 0; k < 32; ++k) s += out_proj_w[i * 32 + k] * Wv[k * 32 + j];
        Wvo[idx] = s;
    }
    if (t < 32) {
        float s = 0.f;
        for (int k = 0; k < 32; ++k) s += out_proj_w[t * 32 + k] * bv[k];
        bvo[t] = s + out_proj_b[t];
    }
    __syncthreads();
    for (int idx = t; idx < 16 * 32; idx += 256) {
        int c = idx >> 5, j = idx & 31;
        float s = 0.f;
        for (int i = 0; i < 32; ++i) s += fc_w[c * 32 + i] * Wvo[i * 32 + j];
        M[idx] = s;
    }
    if (t < 16) {
        float s = 0.f;
        for (int i = 0; i < 32; ++i) s += fc_w[t * 32 + i] * bvo[i];
        bf[t] = s + fc_b[t];
    }
}

extern "C" void kernel_launch(void* const* d_in, const int* in_sizes, int n_in,
                              void* d_out, int out_size, void* d_ws, size_t ws_size,
                              hipStream_t stream) {
    const float* x   = (const float*)d_in[0];
    const int*   ei  = (const int*)d_in[1];
    const float* W1  = (const float*)d_in[2];
    const float* a1s = (const float*)d_in[3];
    const float* a1d = (const float*)d_in[4];
    const float* b1  = (const float*)d_in[5];
    const float* W2  = (const float*)d_in[6];
    const float* a2s = (const float*)d_in[7];
    const float* a2d = (const float*)d_in[8];
    const float* b2  = (const float*)d_in[9];
    const float* ipw = (const float*)d_in[10];
    const float* ipb = (const float*)d_in[11];
    const float* opw = (const float*)d_in[12];
    const float* opb = (const float*)d_in[13];
    const float* fcw = (const float*)d_in[14];
    const float* fcb = (const float*)d_in[15];
    float* out = (float*)d_out;

    int N = in_sizes[0] / 128;
    int E = in_sizes[1] / 2;
    int Et = E + N;
    int NB = (N + BMASK) >> BSHIFT;
    int NTILES = (Et + TILE - 1) / TILE;

    char* ws = (char*)d_ws;
    size_t off = 0;
    auto alloc = [&](size_t bytes) -> void* {
        void* p = ws + off;
        off += bytes;
        off = (off + 255) & ~(size_t)255;
        return p;
    };
    int*   bcount = (int*)alloc(MAXNB * 4);
    int*   bbase  = (int*)alloc(MAXNB * 4);
    int*   gcur   = (int*)alloc(MAXNB * 4);
    unsigned int*   rec  = (unsigned int*)alloc((size_t)Et * 4);
    int*   rowp   = (int*)alloc((size_t)(N + 1) * 4);
    unsigned short* esrc = (unsigned short*)alloc((size_t)Et * 2);
    __hip_bfloat16* h1 = (__hip_bfloat16*)alloc((size_t)N * 64 * 2);
    float* al1s  = (float*)alloc((size_t)N * 8 * 4);
    float* al1d  = (float*)alloc((size_t)N * 8 * 4);
    __hip_bfloat16* h2 = (__hip_bfloat16*)alloc((size_t)N * 32 * 2);
    float* al2s  = (float*)alloc((size_t)N * 8 * 4);
    float* al2d  = (float*)alloc((size_t)N * 8 * 4);
    float* Mf    = (float*)alloc(512 * 4);
    float* bff   = (float*)alloc(16 * 4);
    (void)ws_size; (void)n_in; (void)out_size;

    hipMemsetAsync(bcount, 0, MAXNB * 4, stream);
    bin_count_kernel<<<NTILES, 256, 0, stream>>>(ei, E, Et, NB, bcount);
    bucket_scan_kernel<<<1, 512, 0, stream>>>(bcount, bbase, gcur, NB);
    bin_scatter_kernel<<<NTILES, 256, 0, stream>>>(ei, E, Et, NB, gcur, rec);
    csr_finalize_kernel<<<NB, 256, 0, stream>>>(rec, bcount, bbase, rowp, esrc, N, Et);

    gemm1_mfma_kernel<<<(N + 63) / 64, 256, 0, stream>>>(x, W1, a1s, a1d, h1, al1s, al1d, N);
    fold_kernel<<<1, 256, 0, stream>>>(ipw, ipb, opw, opb, fcw, fcb, Mf, bff);
    gat_agg64_g2_kernel<<<(N + 3) / 4, 256, 0, stream>>>(
        rowp, esrc, h1, al1s, al1d, b1, W2, a2s, a2d, h2, al2s, al2d, N);
    gat_agg32_fin_kernel<<<(N + 7) / 8, 256, 0, stream>>>(
        rowp, esrc, h2, al2s, al2d, b2, Mf, bff, out, N);
}